// Round 4
// baseline (91.089 us; speedup 1.0000x reference)
//
#include <hip/hip_runtime.h>

// Problem constants (from reference)
#define N_IDEAS 5
#define N_EXPERTS 10
#define OUT_DIM 784          // 28*28
#define CHUNKS 196           // OUT_DIM / 4 (float4 chunks per sample)
#define BATCH 32768
#define CAP 32768            // bucket capacity per expert (worst case)
#define SPG 16               // samples per wave-group in kernel B

// ---------------- Kernel A: bucket samples by expert ----------------
// Per-wave ballot aggregation: 10 ballots, 10 atomics per wave (not 64).
__global__ __launch_bounds__(256) void bucket_build(
    const int* __restrict__ labels, int* __restrict__ cnt, int* __restrict__ bucket)
{
    const int i    = blockIdx.x * 256 + threadIdx.x;   // grid covers BATCH exactly
    const int lane = threadIdx.x & 63;
    const int lab  = labels[i];
#pragma unroll
    for (int e = 0; e < N_EXPERTS; ++e) {
        const unsigned long long m = __ballot(lab == e);
        if (lab == e) {
            const int leader = __ffsll(m) - 1;
            const int rank   = __popcll(m & ((1ull << lane) - 1ull));
            int base = 0;
            if (lane == leader) base = atomicAdd(&cnt[e], (int)__popcll(m));
            base = __shfl(base, leader, 64);
            bucket[e * CAP + base + rank] = i;
        }
    }
}

// ---------------- Kernel B: apply expert, pure-store hot loop ----------------
// One wave per block. Wave self-assigns (expert e, group g) from device counts.
// W for this wave's chunks: 4 tiles x 5 float4 = 80 VGPR, loaded once.
// Per sample: uniform scalar sid/x loads + 65 FMA + 4 contiguous wave-stores.
__global__ __launch_bounds__(64) void moe_apply(
    const float* __restrict__ x, const float* __restrict__ W,
    const float* __restrict__ b, const int* __restrict__ cnt,
    const int* __restrict__ bucket, float4* __restrict__ out)
{
    const int lane = threadIdx.x;                       // 0..63
    const int wid  = __builtin_amdgcn_readfirstlane(blockIdx.x);

    // map wave -> (expert, group) by scanning device-side counts (scalar)
    int e = -1, g = 0, acc = 0;
#pragma unroll
    for (int k = 0; k < N_EXPERTS; ++k) {
        const int gk = (cnt[k] + (SPG - 1)) >> 4;       // ceil(cnt/16)
        if (e < 0 && wid < acc + gk) { e = k; g = wid - acc; }
        acc += gk;
    }
    if (e < 0) return;                                  // ghost wave
    const int ce = cnt[e];
    const int s0 = g * SPG;
    const int s1 = (s0 + SPG < ce) ? s0 + SPG : ce;

    // ---- W/b prologue into registers (per-thread chunks: lane, 64+lane, 128+lane, tail)
    const float4* Wg = (const float4*)W;                // 980 f4 per expert
    const float4* bg = (const float4*)b;                // 196 f4 per expert
    const int c0 = lane, c1 = 64 + lane, c2 = 128 + lane, c3 = 192 + (lane & 3);
    float4 w0[5], w1[5], w2[5], w3[5];
#pragma unroll
    for (int r = 0; r < 5; ++r) {
        w0[r] = Wg[e * 980 + c0 * 5 + r];
        w1[r] = Wg[e * 980 + c1 * 5 + r];
        w2[r] = Wg[e * 980 + c2 * 5 + r];
        w3[r] = Wg[e * 980 + c3 * 5 + r];
    }
    const float4 b0 = bg[e * 196 + c0], b1 = bg[e * 196 + c1];
    const float4 b2 = bg[e * 196 + c2], b3 = bg[e * 196 + c3];

    const int* bl = bucket + e * CAP;
    for (int s = s0; s < s1; ++s) {
        const int sid = bl[s];                          // wave-uniform -> s_load
        const float* xp = x + sid * N_IDEAS;            // uniform scalar loads
        const float x0 = xp[0], x1 = xp[1], x2 = xp[2], x3 = xp[3], x4 = xp[4];
        const size_t ob = (size_t)sid * CHUNKS;

        float4 r;
#define ROW(W4, BB) \
        r.x = BB.x + W4[0].x*x0 + W4[0].y*x1 + W4[0].z*x2 + W4[0].w*x3 + W4[1].x*x4; \
        r.y = BB.y + W4[1].y*x0 + W4[1].z*x1 + W4[1].w*x2 + W4[2].x*x3 + W4[2].y*x4; \
        r.z = BB.z + W4[2].z*x0 + W4[2].w*x1 + W4[3].x*x2 + W4[3].y*x3 + W4[3].z*x4; \
        r.w = BB.w + W4[3].w*x0 + W4[4].x*x1 + W4[4].y*x2 + W4[4].z*x3 + W4[4].w*x4;
        ROW(w0, b0); out[ob + c0] = r;                  // 1024B contiguous wave-store
        ROW(w1, b1); out[ob + c1] = r;
        ROW(w2, b2); out[ob + c2] = r;
        if (lane < 4) { ROW(w3, b3); out[ob + 192 + lane] = r; }  // 64B tail
#undef ROW
    }
}

// ---------------- Fallback (round-2 LDS kernel) if ws too small ----------------
#define CTILE 28
#define SPB 128
#define BLOCKF 256
__global__ __launch_bounds__(BLOCKF) void moe_gather_gemv_lds(
    const float* __restrict__ x, const int* __restrict__ labels,
    const float* __restrict__ W, const float* __restrict__ b,
    float4* __restrict__ out)
{
    __shared__ float Wl[N_EXPERTS * CTILE * 20];
    __shared__ float bl[N_EXPERTS * CTILE * 4];
    __shared__ float xl[SPB * N_IDEAS];
    __shared__ int   ll[SPB];
    const int tid = threadIdx.x, sg = blockIdx.x, ct = blockIdx.y;
    {
        const float4* Wg = (const float4*)W; float4* Wl4 = (float4*)Wl;
        for (int i = tid; i < N_EXPERTS * 140; i += BLOCKF) {
            const int e = i / 140, r = i - e * 140;
            Wl4[e * 140 + r] = Wg[e * 980 + ct * 140 + r];
        }
        const float4* bg = (const float4*)b; float4* bl4 = (float4*)bl;
        for (int i = tid; i < N_EXPERTS * CTILE; i += BLOCKF) {
            const int e = i / CTILE, r = i - e * CTILE;
            bl4[e * CTILE + r] = bg[e * 196 + ct * CTILE + r];
        }
        const float4* xg = (const float4*)x; float4* xl4 = (float4*)xl;
        for (int i = tid; i < (SPB * N_IDEAS) / 4; i += BLOCKF)
            xl4[i] = xg[sg * 160 + i];
        if (tid < SPB / 4) ((int4*)ll)[tid] = ((const int4*)labels)[sg * (SPB / 4) + tid];
    }
    __syncthreads();
    const size_t outBase = (size_t)sg * SPB * CHUNKS + (size_t)ct * CTILE;
#pragma unroll
    for (int k = 0; k < (SPB * CTILE) / BLOCKF; ++k) {
        const int i = tid + k * BLOCKF;
        const int s_l = i / CTILE, c_l = i - s_l * CTILE;
        const int e = ll[s_l];
        const float* xp = &xl[s_l * N_IDEAS];
        const float x0 = xp[0], x1 = xp[1], x2 = xp[2], x3 = xp[3], x4 = xp[4];
        const float4* wp = (const float4*)&Wl[(e * CTILE + c_l) * 20];
        const float4 w0 = wp[0], w1 = wp[1], w2 = wp[2], w3 = wp[3], w4 = wp[4];
        const float4 bb = ((const float4*)&bl[(e * CTILE + c_l) * 4])[0];
        float4 r;
        r.x = bb.x + w0.x*x0 + w0.y*x1 + w0.z*x2 + w0.w*x3 + w1.x*x4;
        r.y = bb.y + w1.y*x0 + w1.z*x1 + w1.w*x2 + w2.x*x3 + w2.y*x4;
        r.z = bb.z + w2.z*x0 + w2.w*x1 + w3.x*x2 + w3.y*x3 + w3.z*x4;
        r.w = bb.w + w3.w*x0 + w4.x*x1 + w4.y*x2 + w4.z*x3 + w4.w*x4;
        out[outBase + (size_t)s_l * CHUNKS + c_l] = r;
    }
}

extern "C" void kernel_launch(void* const* d_in, const int* in_sizes, int n_in,
                              void* d_out, int out_size, void* d_ws, size_t ws_size,
                              hipStream_t stream) {
    const float* x      = (const float*)d_in[0];
    const int*   labels = (const int*)d_in[1];
    const float* W      = (const float*)d_in[2];
    const float* b      = (const float*)d_in[3];
    float4* out = (float4*)d_out;

    const size_t need = 256 + (size_t)N_EXPERTS * CAP * sizeof(int);
    if (ws_size >= need) {
        int* cnt    = (int*)d_ws;                        // 10 counters
        int* bucket = (int*)((char*)d_ws + 256);         // 10 x 32768 ids
        hipMemsetAsync(d_ws, 0, 64, stream);             // zero counters (capturable)
        bucket_build<<<BATCH / 256, 256, 0, stream>>>(labels, cnt, bucket);
        // worst-case wave-groups: ceil(32768/16) + 9 = 2057 -> launch 2080 waves
        moe_apply<<<2080, 64, 0, stream>>>(x, W, b, cnt, bucket, out);
    } else {
        dim3 grid(BATCH / SPB, OUT_DIM / (CTILE * 4));   // 256 x 7
        moe_gather_gemv_lds<<<grid, dim3(BLOCKF), 0, stream>>>(x, labels, W, b, out);
    }
}

// Round 5
// 33.960 us; speedup vs baseline: 2.6823x; 2.6823x over previous
//
#include <hip/hip_runtime.h>

// Problem constants (from reference)
#define N_IDEAS 5
#define N_EXPERTS 10
#define OUT_DIM 784          // 28*28
#define CHUNKS 196           // OUT_DIM / 4 (float4 chunks per sample)
#define BATCH 32768
#define CAP 32768            // bucket capacity per expert (worst case)
#define SPG 16               // samples per wave-group in kernel B
#define CNT_STRIDE 256       // ints: pad counters 1KB apart (separate L2 lines)

// ---------------- Kernel A: bucket samples by expert ----------------
// LDS-aggregated histogram: ballot -> per-wave counts in LDS -> per-block
// prefix -> ONE global atomic per (block,expert), counters 1KB apart.
// 64 blocks x 512 thr: 64 serialized atomics per line (~1us), not 5120.
__global__ __launch_bounds__(512) void bucket_build(
    const int* __restrict__ labels, int* __restrict__ gcnt, int* __restrict__ bucket)
{
    __shared__ int wcnt[8][N_EXPERTS];
    __shared__ int wbase[8][N_EXPERTS];
    __shared__ int gbase[N_EXPERTS];
    const int tid  = threadIdx.x;
    const int lane = tid & 63, w = tid >> 6;
    const int gid  = blockIdx.x * 512 + tid;      // grid covers BATCH exactly
    const int lab  = labels[gid];
    int myrank = 0;
#pragma unroll
    for (int e = 0; e < N_EXPERTS; ++e) {
        const unsigned long long m = __ballot(lab == e);
        if (lane == 0) wcnt[w][e] = (int)__popcll(m);
        if (lab == e)  myrank = (int)__popcll(m & ((1ull << lane) - 1ull));
    }
    __syncthreads();
    if (tid < N_EXPERTS) {                        // e = tid
        int base = 0;
#pragma unroll
        for (int ww = 0; ww < 8; ++ww) { wbase[ww][tid] = base; base += wcnt[ww][tid]; }
        gbase[tid] = atomicAdd(&gcnt[tid * CNT_STRIDE], base);
    }
    __syncthreads();
    const int pos = gbase[lab] + wbase[w][lab] + myrank;
    bucket[lab * CAP + pos] = gid;
}

// ---------------- Kernel B: apply expert, pure-store hot loop ----------------
// One wave per block; wave self-assigns (expert, 16-sample group). W for the
// wave's chunks: 80 VGPR loaded once. Per sample: uniform scalar sid/x loads
// (1-deep sid prefetch) + 65 FMA + 4 contiguous wave-stores (3136B row).
__global__ __launch_bounds__(64) void moe_apply(
    const float* __restrict__ x, const float* __restrict__ W,
    const float* __restrict__ b, const int* __restrict__ gcnt,
    const int* __restrict__ bucket, float4* __restrict__ out)
{
    const int lane = threadIdx.x;                       // 0..63
    const int wid  = __builtin_amdgcn_readfirstlane(blockIdx.x);

    // map wave -> (expert, group) by scanning device-side padded counts
    int e = -1, g = 0, acc = 0;
#pragma unroll
    for (int k = 0; k < N_EXPERTS; ++k) {
        const int ck = gcnt[k * CNT_STRIDE];
        const int gk = (ck + (SPG - 1)) >> 4;           // ceil(cnt/16)
        if (e < 0 && wid < acc + gk) { e = k; g = wid - acc; }
        acc += gk;
    }
    if (e < 0) return;                                  // ghost wave
    const int ce = gcnt[e * CNT_STRIDE];
    const int s0 = g * SPG;
    const int s1 = (s0 + SPG < ce) ? s0 + SPG : ce;

    // ---- W/b prologue into registers (chunks: lane, 64+lane, 128+lane, tail)
    const float4* Wg = (const float4*)W;                // 980 f4 per expert
    const float4* bg = (const float4*)b;                // 196 f4 per expert
    const int c0 = lane, c1 = 64 + lane, c2 = 128 + lane, c3 = 192 + (lane & 3);
    float4 w0[5], w1[5], w2[5], w3[5];
#pragma unroll
    for (int r = 0; r < 5; ++r) {
        w0[r] = Wg[e * 980 + c0 * 5 + r];
        w1[r] = Wg[e * 980 + c1 * 5 + r];
        w2[r] = Wg[e * 980 + c2 * 5 + r];
        w3[r] = Wg[e * 980 + c3 * 5 + r];
    }
    const float4 b0 = bg[e * 196 + c0], b1 = bg[e * 196 + c1];
    const float4 b2 = bg[e * 196 + c2], b3 = bg[e * 196 + c3];

    const int* bl = bucket + e * CAP;
    int sid = bl[s0];                                   // 1-deep sid prefetch
    for (int s = s0; s < s1; ++s) {
        const int sidn = (s + 1 < s1) ? bl[s + 1] : sid;
        const float* xp = x + sid * N_IDEAS;            // uniform -> s_load
        const float x0 = xp[0], x1 = xp[1], x2 = xp[2], x3 = xp[3], x4 = xp[4];
        const size_t ob = (size_t)sid * CHUNKS;

        float4 r;
#define ROW(W4, BB) \
        r.x = BB.x + W4[0].x*x0 + W4[0].y*x1 + W4[0].z*x2 + W4[0].w*x3 + W4[1].x*x4; \
        r.y = BB.y + W4[1].y*x0 + W4[1].z*x1 + W4[1].w*x2 + W4[2].x*x3 + W4[2].y*x4; \
        r.z = BB.z + W4[2].z*x0 + W4[2].w*x1 + W4[3].x*x2 + W4[3].y*x3 + W4[3].z*x4; \
        r.w = BB.w + W4[3].w*x0 + W4[4].x*x1 + W4[4].y*x2 + W4[4].z*x3 + W4[4].w*x4;
        ROW(w0, b0); out[ob + c0] = r;                  // 1024B contiguous
        ROW(w1, b1); out[ob + c1] = r;
        ROW(w2, b2); out[ob + c2] = r;
        if (lane < 4) { ROW(w3, b3); out[ob + 192 + lane] = r; }  // 64B tail
#undef ROW
        sid = sidn;
    }
}

// ---------------- Fallback (round-2 LDS kernel) if ws too small ----------------
#define CTILE 28
#define SPB 128
#define BLOCKF 256
__global__ __launch_bounds__(BLOCKF) void moe_gather_gemv_lds(
    const float* __restrict__ x, const int* __restrict__ labels,
    const float* __restrict__ W, const float* __restrict__ b,
    float4* __restrict__ out)
{
    __shared__ float Wl[N_EXPERTS * CTILE * 20];
    __shared__ float bl[N_EXPERTS * CTILE * 4];
    __shared__ float xl[SPB * N_IDEAS];
    __shared__ int   ll[SPB];
    const int tid = threadIdx.x, sg = blockIdx.x, ct = blockIdx.y;
    {
        const float4* Wg = (const float4*)W; float4* Wl4 = (float4*)Wl;
        for (int i = tid; i < N_EXPERTS * 140; i += BLOCKF) {
            const int e = i / 140, r = i - e * 140;
            Wl4[e * 140 + r] = Wg[e * 980 + ct * 140 + r];
        }
        const float4* bg = (const float4*)b; float4* bl4 = (float4*)bl;
        for (int i = tid; i < N_EXPERTS * CTILE; i += BLOCKF) {
            const int e = i / CTILE, r = i - e * CTILE;
            bl4[e * CTILE + r] = bg[e * 196 + ct * CTILE + r];
        }
        const float4* xg = (const float4*)x; float4* xl4 = (float4*)xl;
        for (int i = tid; i < (SPB * N_IDEAS) / 4; i += BLOCKF)
            xl4[i] = xg[sg * 160 + i];
        if (tid < SPB / 4) ((int4*)ll)[tid] = ((const int4*)labels)[sg * (SPB / 4) + tid];
    }
    __syncthreads();
    const size_t outBase = (size_t)sg * SPB * CHUNKS + (size_t)ct * CTILE;
#pragma unroll
    for (int k = 0; k < (SPB * CTILE) / BLOCKF; ++k) {
        const int i = tid + k * BLOCKF;
        const int s_l = i / CTILE, c_l = i - s_l * CTILE;
        const int e = ll[s_l];
        const float* xp = &xl[s_l * N_IDEAS];
        const float x0 = xp[0], x1 = xp[1], x2 = xp[2], x3 = xp[3], x4 = xp[4];
        const float4* wp = (const float4*)&Wl[(e * CTILE + c_l) * 20];
        const float4 w0 = wp[0], w1 = wp[1], w2 = wp[2], w3 = wp[3], w4 = wp[4];
        const float4 bb = ((const float4*)&bl[(e * CTILE + c_l) * 4])[0];
        float4 r;
        r.x = bb.x + w0.x*x0 + w0.y*x1 + w0.z*x2 + w0.w*x3 + w1.x*x4;
        r.y = bb.y + w1.y*x0 + w1.z*x1 + w1.w*x2 + w2.x*x3 + w2.y*x4;
        r.z = bb.z + w2.z*x0 + w2.w*x1 + w3.x*x2 + w3.y*x3 + w3.z*x4;
        r.w = bb.w + w3.w*x0 + w4.x*x1 + w4.y*x2 + w4.z*x3 + w4.w*x4;
        out[outBase + (size_t)s_l * CHUNKS + c_l] = r;
    }
}

extern "C" void kernel_launch(void* const* d_in, const int* in_sizes, int n_in,
                              void* d_out, int out_size, void* d_ws, size_t ws_size,
                              hipStream_t stream) {
    const float* x      = (const float*)d_in[0];
    const int*   labels = (const int*)d_in[1];
    const float* W      = (const float*)d_in[2];
    const float* b      = (const float*)d_in[3];
    float4* out = (float4*)d_out;

    const size_t cnt_bytes = (size_t)N_EXPERTS * CNT_STRIDE * sizeof(int); // 10KB
    const size_t need = cnt_bytes + (size_t)N_EXPERTS * CAP * sizeof(int);
    if (ws_size >= need) {
        int* gcnt   = (int*)d_ws;                        // padded counters
        int* bucket = (int*)((char*)d_ws + cnt_bytes);   // 10 x 32768 ids
        hipMemsetAsync(d_ws, 0, cnt_bytes, stream);      // zero counters
        bucket_build<<<BATCH / 512, 512, 0, stream>>>(labels, gcnt, bucket);
        // worst-case wave-groups: ceil-sum <= 2057 -> launch 2080 waves
        moe_apply<<<2080, 64, 0, stream>>>(x, W, b, gcnt, bucket, out);
    } else {
        dim3 grid(BATCH / SPB, OUT_DIM / (CTILE * 4));   // 256 x 7
        moe_gather_gemv_lds<<<grid, dim3(BLOCKF), 0, stream>>>(x, labels, W, b, out);
    }
}

// Round 6
// 27.361 us; speedup vs baseline: 3.3292x; 1.2412x over previous
//
#include <hip/hip_runtime.h>

// Problem constants (from reference)
#define N_IDEAS 5
#define N_EXPERTS 10
#define OUT_DIM 784          // 28*28
#define CHUNKS 196           // OUT_DIM / 4 (float4 chunks per sample)
#define BATCH 32768
#define CTILE 28             // chunks per tile (196 = 7*28)
#define NTILES 7
#define SPB 512              // samples per block (persistent slab)
#define BLOCK 256
#define NITER ((SPB * CTILE) / BLOCK)   // 56 hot iterations, exact
#define SADV (BLOCK / CTILE)            // 9
#define CADV (BLOCK - SADV * CTILE)     // 4

// Single fused kernel. Block = (sample slab sg of 512, chunk tile ct of 28).
// Stage W-tile + bias-tile + x-slab + labels ONCE (45.3 KB LDS, one barrier),
// then 56 software-pipelined iterations: prefetch stage k+1's LDS fragments
// (expert id fetched 2 ahead to break the e->W address chain) while doing
// 20 FMA + one float4 store for stage k. Store-BW bound by design.
__global__ __launch_bounds__(BLOCK) void moe_fused(
    const float* __restrict__ x,      // [B, 5]
    const int* __restrict__ labels,   // [B]
    const float* __restrict__ W,      // [E, 784, 5]
    const float* __restrict__ b,      // [E, 784]
    float4* __restrict__ out)         // [B*196]
{
    __shared__ float  Wl[N_EXPERTS * CTILE * 20];   // 22.4 KB  [e][c][20]
    __shared__ float4 bl4[N_EXPERTS * CTILE];       // 4.5 KB   [e][c]
    __shared__ float  xl[SPB * 8];                  // 16 KB    [s][8] (stride 8)
    __shared__ int    ll[SPB];                      // 2 KB

    const int tid = threadIdx.x;
    const int sg  = blockIdx.x;       // sample slab: [sg*512, +512)
    const int ct  = blockIdx.y;       // chunk tile:  [ct*28, +28)

    // ---- one-time staging ----
    {
        const float4* Wg = (const float4*)W;        // 980 f4 per expert
        float4* Wl4 = (float4*)Wl;
        for (int i = tid; i < N_EXPERTS * 140; i += BLOCK) {   // 560f/4
            const int e = i / 140, r = i - e * 140;
            Wl4[e * 140 + r] = Wg[e * 980 + ct * 140 + r];
        }
        const float4* bg = (const float4*)b;        // 196 f4 per expert
        for (int i = tid; i < N_EXPERTS * CTILE; i += BLOCK) {
            const int e = i / CTILE, r = i - e * CTILE;
            bl4[e * CTILE + r] = bg[e * 196 + ct * CTILE + r];
        }
        const float4* xg = (const float4*)x;        // 640 f4 per slab
        for (int i = tid; i < (SPB * N_IDEAS) / 4; i += BLOCK) {
            const float4 v = xg[(size_t)sg * ((SPB * N_IDEAS) / 4) + i];
            const float vv[4] = {v.x, v.y, v.z, v.w};
            const int f0 = i * 4;
#pragma unroll
            for (int j = 0; j < 4; ++j) {           // scatter to stride-8 rows
                const int f = f0 + j;
                const int s = f / 5;
                xl[s * 8 + (f - s * 5)] = vv[j];
            }
        }
        const int4* lg = (const int4*)labels;
        for (int i = tid; i < SPB / 4; i += BLOCK)
            ((int4*)ll)[i] = lg[sg * (SPB / 4) + i];
    }
    __syncthreads();

    // ---- software-pipelined hot loop ----
    const size_t outBase = (size_t)sg * SPB * CHUNKS + (size_t)ct * CTILE;

    int s_c = tid / CTILE;                 // current stage indices
    int c_c = tid - s_c * CTILE;
    int s_n = s_c + SADV, c_n = c_c + CADV;        // next stage indices
    if (c_n >= CTILE) { c_n -= CTILE; ++s_n; }

    int e_n = ll[s_n];                     // expert id, 1 ahead (2 ahead in loop)
    float4 w0, w1, w2, w3, w4, bb;
    float x0, x1, x2, x3, x4;
    {
        const int e_c = ll[s_c];
        const float4* wp = (const float4*)&Wl[(e_c * CTILE + c_c) * 20];
        w0 = wp[0]; w1 = wp[1]; w2 = wp[2]; w3 = wp[3]; w4 = wp[4];
        bb = bl4[e_c * CTILE + c_c];
        const float4 xv = *(const float4*)&xl[s_c * 8];
        x0 = xv.x; x1 = xv.y; x2 = xv.z; x3 = xv.w;
        x4 = xl[s_c * 8 + 4];
    }

#define COMPUTE_R(R)                                                          \
    R.x = bb.x + w0.x*x0 + w0.y*x1 + w0.z*x2 + w0.w*x3 + w1.x*x4;             \
    R.y = bb.y + w1.y*x0 + w1.z*x1 + w1.w*x2 + w2.x*x3 + w2.y*x4;             \
    R.z = bb.z + w2.z*x0 + w2.w*x1 + w3.x*x2 + w3.y*x3 + w3.z*x4;             \
    R.w = bb.w + w3.w*x0 + w4.x*x1 + w4.y*x2 + w4.z*x3 + w4.w*x4;

#pragma unroll 1
    for (int k = 0; k < NITER - 1; ++k) {
        // next-next indices; label prefetched 2 stages ahead (masked: the
        // final iteration's fetch is out-of-range garbage, never used)
        int s_nn = s_n + SADV, c_nn = c_n + CADV;
        if (c_nn >= CTILE) { c_nn -= CTILE; ++s_nn; }
        const int e_nn = ll[s_nn & (SPB - 1)];

        // prefetch stage k+1 fragments (e_n already resolved last iter)
        const float4* wp = (const float4*)&Wl[(e_n * CTILE + c_n) * 20];
        const float4 nw0 = wp[0], nw1 = wp[1], nw2 = wp[2], nw3 = wp[3], nw4 = wp[4];
        const float4 nbb = bl4[e_n * CTILE + c_n];
        const float4 nxv = *(const float4*)&xl[s_n * 8];
        const float  nx4 = xl[s_n * 8 + 4];

        // compute + store stage k (operands loaded last iteration)
        float4 r;
        COMPUTE_R(r)
        out[outBase + (size_t)s_c * CHUNKS + c_c] = r;

        // rotate pipeline registers
        w0 = nw0; w1 = nw1; w2 = nw2; w3 = nw3; w4 = nw4; bb = nbb;
        x0 = nxv.x; x1 = nxv.y; x2 = nxv.z; x3 = nxv.w; x4 = nx4;
        s_c = s_n; c_c = c_n; s_n = s_nn; c_n = c_nn; e_n = e_nn;
    }
    {   // epilogue: last stage
        float4 r;
        COMPUTE_R(r)
        out[outBase + (size_t)s_c * CHUNKS + c_c] = r;
    }
#undef COMPUTE_R
}

extern "C" void kernel_launch(void* const* d_in, const int* in_sizes, int n_in,
                              void* d_out, int out_size, void* d_ws, size_t ws_size,
                              hipStream_t stream) {
    const float* x      = (const float*)d_in[0];
    const int*   labels = (const int*)d_in[1];
    const float* W      = (const float*)d_in[2];
    const float* b      = (const float*)d_in[3];
    float4* out = (float4*)d_out;

    dim3 grid(BATCH / SPB, NTILES);    // 64 x 7 = 448 blocks, ~1.75/CU
    moe_fused<<<grid, dim3(BLOCK), 0, stream>>>(x, labels, W, b, out);
}